// Round 6
// baseline (24850.952 us; speedup 1.0000x reference)
//
#include <hip/hip_runtime.h>
#include <math.h>
#include <stdint.h>

// Replicate XLA numerics: no FMA contraction anywhere.
#pragma clang fp contract(off)

// ---------------- problem constants ----------------
// x_old: (32,3,224,224) f32; x/out: (32,64,56,56) f32
#define NDIST   3612672   // 32*9*112*112 = 882*4096
#define NPMAP   401408    // 32*112*112
#define NPOOL   100352    // 32*3136
#define NSAMP_T 641024    // 313 * 2048 (one thread per (s,r))
#define NMEANB  882       // k_mean1 blocks (4096 elems each)

__device__ __align__(16) float g_dist[NDIST];
__device__ __align__(16) float g_pmap[NPMAP];
__device__ __align__(16) float g_pooled[NPOOL];
__device__ __align__(16) float g_logits[NPOOL];
__device__ float g_partial[NMEANB];
__device__ float g_lmax[32];
__device__ float g_mean[1];
__device__ int   g_sij[18];

// ---------------- NumPy SeedSequence(0) + PCG64 + 32-bit buffered Lemire ----------------
// EXPERIMENT R6: ss_mix fixed to numpy's TRUE mix: x*MIX_MULT_L - y*MIX_MULT_R
// (was XOR in R0-R5 -- corrupted the entropy pool, making every downstream
//  decoding wrong; explains the invariant ~4.2 absmax across all variants).
// Decoding held at best-audit config: low-half-first next32, Lemire-32 thr=4,
// initstate = (gs[0]<<64)|gs[1]  [PCG_128BIT_CONSTANT(seed[0], seed[1])].
__device__ __forceinline__ uint32_t ss_hash(uint32_t value, uint32_t& hc) {
  value ^= hc; hc *= 0x931e8875u; value *= hc; value ^= value >> 16; return value;
}
__device__ __forceinline__ uint32_t ss_mix(uint32_t x, uint32_t y) {
  uint32_t r = x * 0xca01f9ddu - y * 0x4973f715u;   // multiply-SUBTRACT (numpy mix)
  r ^= r >> 16; return r;
}

__global__ void k_rng() {
  if (threadIdx.x != 0 || blockIdx.x != 0) return;
  // SeedSequence(0) entropy pool
  uint32_t pool[4];
  uint32_t hc = 0x43b0d7e5u;                       // INIT_A
  for (int i = 0; i < 4; ++i) pool[i] = ss_hash(0u, hc);
  for (int is = 0; is < 4; ++is)
    for (int id = 0; id < 4; ++id)
      if (is != id) pool[id] = ss_mix(pool[id], ss_hash(pool[is], hc));
  uint32_t hb = 0x8b51f9ddu;                       // INIT_B
  uint32_t w[8];
  for (int i = 0; i < 8; ++i) {
    uint32_t dv = pool[i & 3];
    dv ^= hb; hb *= 0x58f38dedu; dv *= hb; dv ^= dv >> 16; w[i] = dv;
  }
  uint64_t gs[4];
  for (int i = 0; i < 4; ++i) gs[i] = (uint64_t)w[2*i] | ((uint64_t)w[2*i+1] << 32);
  // PCG64 seeding: PCG_128BIT_CONSTANT(seed[0], seed[1]) = seed[0] is HIGH
  const __uint128_t MUL = (((__uint128_t)0x2360ED051FC65DA4ull) << 64) | 0x4385DF649FCCF645ull;
  __uint128_t initstate = (((__uint128_t)gs[0]) << 64) | gs[1];
  __uint128_t initseq   = (((__uint128_t)gs[2]) << 64) | gs[3];
  __uint128_t inc   = (initseq << 1) | 1;
  __uint128_t state = 0;
  state = state * MUL + inc;
  state += initstate;
  state = state * MUL + inc;

  // pcg64_next32: returns LOW half, buffers HIGH half (numpy pcg64_next32)
  bool has32 = false; uint32_t saved32 = 0;
  auto next32 = [&]() -> uint32_t {
    if (has32) { has32 = false; return saved32; }
    state = state * MUL + inc;
    uint64_t xo = (uint64_t)(state >> 64) ^ (uint64_t)state;
    uint32_t rot = (uint32_t)(state >> 122) & 63u;
    uint64_t v = (xo >> rot) | (xo << ((64u - rot) & 63u));   // rotr
    has32 = true; saved32 = (uint32_t)(v >> 32);              // high half buffered
    return (uint32_t)v;                                       // low half first
  };

  // 18 draws of bounded_lemire_uint32(rng=6): rng_excl=7, threshold=(2^32-7)%7=4
  for (int k = 0; k < 18; ++k) {
    uint64_t m = (uint64_t)next32() * 7ull;
    uint32_t leftover = (uint32_t)m;
    if (leftover < 7u) {
      while (leftover < 4u) { m = (uint64_t)next32() * 7ull; leftover = (uint32_t)m; }
    }
    g_sij[k] = (int)(uint32_t)(m >> 32) - 3;
  }
}

// ---------------- distance: per-patch squared-diff 7x7 stride-2 window sums ----------------
__global__ __launch_bounds__(256) void k_dist(const float* __restrict__ xold) {
  int idx = blockIdx.x * 256 + threadIdx.x;
  if (idx >= NDIST) return;
  int ox = idx % 112; int tt = idx / 112;
  int oy = tt % 112;  tt /= 112;
  int p = tt % 9;     int b = tt / 9;
  int si = g_sij[p], sj = g_sij[9 + p];
  const float* xb = xold + (size_t)b * 3 * 224 * 224;
  float acc = 0.f;
  for (int kh = 0; kh < 7; ++kh) {
    int hb = 2 * oy + kh - 3;
    int hs = hb + si;
    for (int kw = 0; kw < 7; ++kw) {
      int wb = 2 * ox + kw - 3;
      int wsf = wb + sj;
      float s = 0.f;
      for (int c = 0; c < 3; ++c) {
        const float* xc = xb + c * 224 * 224;
        float bv = (hb >= 0 && hb < 224 && wb >= 0 && wb < 224) ? xc[hb * 224 + wb] : 0.f;
        float sv = (hs >= 0 && hs < 224 && wsf >= 0 && wsf < 224) ? xc[hs * 224 + wsf] : 0.f;
        float d = bv - sv;
        s = s + d * d;              // channel sum, in order
      }
      acc = acc + s;                // window sum, row-major order
    }
  }
  g_dist[idx] = acc;
}

// ---------------- global mean: deterministic two-stage reduce ----------------
__global__ __launch_bounds__(256) void k_mean1() {
  __shared__ float red[256];
  int base = blockIdx.x * 4096;
  float acc = 0.f;
  #pragma unroll
  for (int i = 0; i < 4; ++i) {
    float4 v = *(const float4*)(g_dist + base + threadIdx.x * 4 + i * 1024);
    acc = acc + v.x + v.y + v.z + v.w;
  }
  red[threadIdx.x] = acc;
  __syncthreads();
  for (int s = 128; s > 0; s >>= 1) {
    if (threadIdx.x < s) red[threadIdx.x] += red[threadIdx.x + s];
    __syncthreads();
  }
  if (threadIdx.x == 0) g_partial[blockIdx.x] = red[0];
}
__global__ void k_mean2() {
  if (threadIdx.x != 0 || blockIdx.x != 0) return;
  float acc = 0.f;
  for (int i = 0; i < NMEANB; ++i) acc = acc + g_partial[i];
  g_mean[0] = acc / 3612672.0f;
}

// ---------------- pmap = ((sum_p exp(-d/m/2))/9)^2 ----------------
__global__ __launch_bounds__(256) void k_prob1() {
  int idx = blockIdx.x * 256 + threadIdx.x;
  if (idx >= NPMAP) return;
  int xy = idx % 12544; int b = idx / 12544;
  float m = g_mean[0];
  float ssum = 0.f;
  for (int p = 0; p < 9; ++p) {
    float d = g_dist[(size_t)(b * 9 + p) * 12544 + xy];
    float t = (-d / m) / 2.0f;                      // / BW^2 == /1.0 exact
    float e = expf(t);
    ssum = ssum + e;
  }
  float q = ssum / 9.0f;
  g_pmap[idx] = q * q;                              // ** (1/TEMP) == ^2
}

// ---------------- min-pool 3x3 stride 2 pad 1 ----------------
__global__ __launch_bounds__(256) void k_pool() {
  int idx = blockIdx.x * 256 + threadIdx.x;
  if (idx >= NPOOL) return;
  int ox = idx % 56; int tt = idx / 56;
  int oy = tt % 56;  int b = tt / 56;
  float mn = INFINITY;
  for (int kh = 0; kh < 3; ++kh) {
    int y = 2 * oy - 1 + kh; if (y < 0 || y >= 112) continue;
    for (int kw = 0; kw < 3; ++kw) {
      int x = 2 * ox - 1 + kw; if (x < 0 || x >= 112) continue;
      mn = fminf(mn, g_pmap[(size_t)(b * 112 + y) * 112 + x]);
    }
  }
  g_pooled[idx] = mn;
}

// ---------------- per-b row sum, logits = logf(p/S + 1e-8), row max ----------------
__global__ void k_norm() {
  int b = threadIdx.x;
  if (b >= 32 || blockIdx.x != 0) return;
  const float* P = g_pooled + b * 3136;
  float s = 0.f;
  for (int i = 0; i < 3136; ++i) s = s + P[i];
  float lm = -INFINITY;
  for (int i = 0; i < 3136; ++i) {
    float fl = P[i] / s;
    float lg = logf(fl + 1e-8f);
    g_logits[b * 3136 + i] = lg;
    lm = fmaxf(lm, lg);
  }
  g_lmax[b] = lm;
}

// ---------------- out = x ----------------
__global__ __launch_bounds__(256) void k_copy(const float4* __restrict__ x, float4* __restrict__ out) {
  int i = blockIdx.x * 256 + threadIdx.x;           // 1,605,632 float4 exactly
  out[i] = x[i];
}

// ---------------- JAX threefry2x32, key = (0, 42), partitionable 32-bit bits ----------------
__device__ __forceinline__ uint32_t rotl32(uint32_t x, int r) { return (x << r) | (x >> (32 - r)); }
__device__ __forceinline__ void threefry2x32(uint32_t x0, uint32_t x1, uint32_t& o0, uint32_t& o1) {
  const uint32_t ks0 = 0u, ks1 = 42u, ks2 = 0x1BD11BDAu ^ 0u ^ 42u;
  x0 += ks0; x1 += ks1;
#define TFR(r) { x0 += x1; x1 = rotl32(x1, (r)); x1 ^= x0; }
  TFR(13) TFR(15) TFR(26) TFR(6)  x0 += ks1; x1 += ks2 + 1u;
  TFR(17) TFR(29) TFR(16) TFR(24) x0 += ks2; x1 += ks0 + 2u;
  TFR(13) TFR(15) TFR(26) TFR(6)  x0 += ks0; x1 += ks1 + 3u;
  TFR(17) TFR(29) TFR(16) TFR(24) x0 += ks1; x1 += ks2 + 4u;
  TFR(13) TFR(15) TFR(26) TFR(6)  x0 += ks2; x1 += ks0 + 5u;
#undef TFR
  o0 = x0; o1 = x1;
}

__device__ __forceinline__ uint32_t random_bits_at(uint32_t idx) {
  uint32_t o0, o1; threefry2x32(0u, idx, o0, o1);   // counter = (hi,lo) of flat idx
  return o0 ^ o1;                                    // 32-bit partitionable combine
}

// Exact-value gumbel (OCML logf).
__device__ __forceinline__ float gumbel_ocml(uint32_t mant) {
  float uni;
  if (mant == 0u) uni = 1.17549435e-38f;            // max(tiny, 0*(1-tiny)+tiny)
  else uni = __uint_as_float(0x3f800000u | mant) - 1.0f;  // exact
  float l1 = logf(uni);
  float n1 = -l1;
  float l2 = logf(n1);
  return -l2;
}

// Conservative MONOTONE upper bound on any sane logf-based gumbel.
__device__ float gumbel_ub(uint32_t mant) {
  double u = (mant == 0u) ? 1.17549435e-38 : (double)mant * 1.1920928955078125e-07;
  double v = -log(u);
  double vlb = v - 1e-6;
  if (vlb < 1e-40) return 1e30f;
  return (float)(-log(vlb) + 1e-4);
}

// smallest mant whose fl(Lmax + gumbel_ub(mant)) > M  (monotone -> binary search)
__device__ uint32_t find_mstar(float M, float Lm) {
  uint32_t lo = 0u, hi = 1u << 23;
  while (lo < hi) {
    uint32_t mid = (lo + hi) >> 1;
    float v = Lm + gumbel_ub(mid);
    if (v > M) hi = mid; else lo = mid + 1u;
  }
  return lo;
}

// ---------------- categorical sampling: one thread per (s,r), zero out winner ----------------
__global__ __launch_bounds__(256) void k_sample(float* __restrict__ out) {
  int t = blockIdx.x * 256 + threadIdx.x;
  if (t >= NSAMP_T) return;
  int r = t & 2047;                 // row in [0,2048)
  int b = r >> 6;
  const float* L = g_logits + b * 3136;
  float Lm = g_lmax[b];
  uint32_t base = (uint32_t)t * 3136u;   // flat gumbel index base, < 2^31
  float M = -INFINITY; int jstar = 0;
  uint32_t mstar = 0u;
  for (int j = 0; j < 3136; ++j) {
    uint32_t bits = random_bits_at(base + (uint32_t)j);
    uint32_t mant = bits >> 9;
    if (mant < mstar) continue;     // sound skip: val <= Lm + gumbel_ub <= M
    float val = L[j] + gumbel_ocml(mant);
    if (val > M) { M = val; jstar = j; mstar = find_mstar(M, Lm); }
  }
  out[(size_t)r * 3136 + (size_t)jstar] = 0.0f;
}

// ---------------- launch ----------------
extern "C" void kernel_launch(void* const* d_in, const int* in_sizes, int n_in,
                              void* d_out, int out_size, void* d_ws, size_t ws_size,
                              hipStream_t stream) {
  (void)in_sizes; (void)n_in; (void)d_ws; (void)ws_size; (void)out_size;
  const float* x_old = (const float*)d_in[0];
  const float* x     = (const float*)d_in[1];
  float* out = (float*)d_out;

  k_rng  <<<1,     64, 0, stream>>>();
  k_dist <<<14112, 256, 0, stream>>>(x_old);
  k_mean1<<<NMEANB,256, 0, stream>>>();
  k_mean2<<<1,     64, 0, stream>>>();
  k_prob1<<<1568,  256, 0, stream>>>();
  k_pool <<<392,   256, 0, stream>>>();
  k_norm <<<1,     64, 0, stream>>>();
  k_copy <<<6272,  256, 0, stream>>>((const float4*)x, (float4*)out);
  k_sample<<<2504, 256, 0, stream>>>(out);
}

// Round 7
// 5943.483 us; speedup vs baseline: 4.1812x; 4.1812x over previous
//
#include <hip/hip_runtime.h>
#include <math.h>
#include <stdint.h>

// Replicate XLA numerics: no FMA contraction anywhere.
#pragma clang fp contract(off)

// ---------------- problem constants ----------------
// x_old: (32,3,224,224) f32; x/out: (32,64,56,56) f32
#define NDIST   3612672   // 32*9*112*112 = 882*4096
#define NPMAP   401408    // 32*112*112
#define NPOOL   100352    // 32*3136
#define NSAMP_T 641024    // 313 * 2048 (one task per (s,r))
#define NTASK2  1282048   // NSAMP_T * 2 half-row tasks
#define NMEANB  882       // k_mean1 blocks (4096 elems each)

__device__ __align__(16) float g_dist[NDIST];
__device__ __align__(16) float g_pmap[NPMAP];
__device__ __align__(16) float g_pooled[NPOOL];
__device__ __align__(16) float g_logits[NPOOL];
__device__ __align__(16) float g_pM[NTASK2];
__device__ __align__(16) int   g_pJ[NTASK2];
__device__ float g_partial[NMEANB];
__device__ float g_lmax[32];
__device__ float g_mean[1];
__device__ int   g_sij[18];

// ---------------- NumPy SeedSequence(0) + PCG64 + 32-bit buffered Lemire ----------------
// VERIFIED R6 (absmax=0): mix = x*L - y*R; low-half-first next32; Lemire-32 thr=4;
// initstate = (gs[0]<<64)|gs[1].
__device__ __forceinline__ uint32_t ss_hash(uint32_t value, uint32_t& hc) {
  value ^= hc; hc *= 0x931e8875u; value *= hc; value ^= value >> 16; return value;
}
__device__ __forceinline__ uint32_t ss_mix(uint32_t x, uint32_t y) {
  uint32_t r = x * 0xca01f9ddu - y * 0x4973f715u;   // multiply-SUBTRACT (numpy mix)
  r ^= r >> 16; return r;
}

__global__ void k_rng() {
  if (threadIdx.x != 0 || blockIdx.x != 0) return;
  uint32_t pool[4];
  uint32_t hc = 0x43b0d7e5u;                       // INIT_A
  for (int i = 0; i < 4; ++i) pool[i] = ss_hash(0u, hc);
  for (int is = 0; is < 4; ++is)
    for (int id = 0; id < 4; ++id)
      if (is != id) pool[id] = ss_mix(pool[id], ss_hash(pool[is], hc));
  uint32_t hb = 0x8b51f9ddu;                       // INIT_B
  uint32_t w[8];
  for (int i = 0; i < 8; ++i) {
    uint32_t dv = pool[i & 3];
    dv ^= hb; hb *= 0x58f38dedu; dv *= hb; dv ^= dv >> 16; w[i] = dv;
  }
  uint64_t gs[4];
  for (int i = 0; i < 4; ++i) gs[i] = (uint64_t)w[2*i] | ((uint64_t)w[2*i+1] << 32);
  const __uint128_t MUL = (((__uint128_t)0x2360ED051FC65DA4ull) << 64) | 0x4385DF649FCCF645ull;
  __uint128_t initstate = (((__uint128_t)gs[0]) << 64) | gs[1];
  __uint128_t initseq   = (((__uint128_t)gs[2]) << 64) | gs[3];
  __uint128_t inc   = (initseq << 1) | 1;
  __uint128_t state = 0;
  state = state * MUL + inc;
  state += initstate;
  state = state * MUL + inc;

  bool has32 = false; uint32_t saved32 = 0;
  auto next32 = [&]() -> uint32_t {
    if (has32) { has32 = false; return saved32; }
    state = state * MUL + inc;
    uint64_t xo = (uint64_t)(state >> 64) ^ (uint64_t)state;
    uint32_t rot = (uint32_t)(state >> 122) & 63u;
    uint64_t v = (xo >> rot) | (xo << ((64u - rot) & 63u));   // rotr
    has32 = true; saved32 = (uint32_t)(v >> 32);              // high half buffered
    return (uint32_t)v;                                       // low half first
  };

  for (int k = 0; k < 18; ++k) {
    uint64_t m = (uint64_t)next32() * 7ull;
    uint32_t leftover = (uint32_t)m;
    if (leftover < 7u) {
      while (leftover < 4u) { m = (uint64_t)next32() * 7ull; leftover = (uint32_t)m; }
    }
    g_sij[k] = (int)(uint32_t)(m >> 32) - 3;
  }
}

// ---------------- distance: per-patch squared-diff 7x7 stride-2 window sums ----------------
__global__ __launch_bounds__(256) void k_dist(const float* __restrict__ xold) {
  int idx = blockIdx.x * 256 + threadIdx.x;
  if (idx >= NDIST) return;
  int ox = idx % 112; int tt = idx / 112;
  int oy = tt % 112;  tt /= 112;
  int p = tt % 9;     int b = tt / 9;
  int si = g_sij[p], sj = g_sij[9 + p];
  const float* xb = xold + (size_t)b * 3 * 224 * 224;
  float acc = 0.f;
  for (int kh = 0; kh < 7; ++kh) {
    int hb = 2 * oy + kh - 3;
    int hs = hb + si;
    for (int kw = 0; kw < 7; ++kw) {
      int wb = 2 * ox + kw - 3;
      int wsf = wb + sj;
      float s = 0.f;
      for (int c = 0; c < 3; ++c) {
        const float* xc = xb + c * 224 * 224;
        float bv = (hb >= 0 && hb < 224 && wb >= 0 && wb < 224) ? xc[hb * 224 + wb] : 0.f;
        float sv = (hs >= 0 && hs < 224 && wsf >= 0 && wsf < 224) ? xc[hs * 224 + wsf] : 0.f;
        float d = bv - sv;
        s = s + d * d;              // channel sum, in order
      }
      acc = acc + s;                // window sum, row-major order
    }
  }
  g_dist[idx] = acc;
}

// ---------------- global mean: deterministic two-stage reduce ----------------
__global__ __launch_bounds__(256) void k_mean1() {
  __shared__ float red[256];
  int base = blockIdx.x * 4096;
  float acc = 0.f;
  #pragma unroll
  for (int i = 0; i < 4; ++i) {
    float4 v = *(const float4*)(g_dist + base + threadIdx.x * 4 + i * 1024);
    acc = acc + v.x + v.y + v.z + v.w;
  }
  red[threadIdx.x] = acc;
  __syncthreads();
  for (int s = 128; s > 0; s >>= 1) {
    if (threadIdx.x < s) red[threadIdx.x] += red[threadIdx.x + s];
    __syncthreads();
  }
  if (threadIdx.x == 0) g_partial[blockIdx.x] = red[0];
}
__global__ void k_mean2() {
  if (threadIdx.x != 0 || blockIdx.x != 0) return;
  float acc = 0.f;
  for (int i = 0; i < NMEANB; ++i) acc = acc + g_partial[i];
  g_mean[0] = acc / 3612672.0f;
}

// ---------------- pmap = ((sum_p exp(-d/m/2))/9)^2 ----------------
__global__ __launch_bounds__(256) void k_prob1() {
  int idx = blockIdx.x * 256 + threadIdx.x;
  if (idx >= NPMAP) return;
  int xy = idx % 12544; int b = idx / 12544;
  float m = g_mean[0];
  float ssum = 0.f;
  for (int p = 0; p < 9; ++p) {
    float d = g_dist[(size_t)(b * 9 + p) * 12544 + xy];
    float t = (-d / m) / 2.0f;                      // / BW^2 == /1.0 exact
    float e = expf(t);
    ssum = ssum + e;
  }
  float q = ssum / 9.0f;
  g_pmap[idx] = q * q;                              // ** (1/TEMP) == ^2
}

// ---------------- min-pool 3x3 stride 2 pad 1 ----------------
__global__ __launch_bounds__(256) void k_pool() {
  int idx = blockIdx.x * 256 + threadIdx.x;
  if (idx >= NPOOL) return;
  int ox = idx % 56; int tt = idx / 56;
  int oy = tt % 56;  int b = tt / 56;
  float mn = INFINITY;
  for (int kh = 0; kh < 3; ++kh) {
    int y = 2 * oy - 1 + kh; if (y < 0 || y >= 112) continue;
    for (int kw = 0; kw < 3; ++kw) {
      int x = 2 * ox - 1 + kw; if (x < 0 || x >= 112) continue;
      mn = fminf(mn, g_pmap[(size_t)(b * 112 + y) * 112 + x]);
    }
  }
  g_pooled[idx] = mn;
}

// ---------------- per-b row sum, logits = logf(p/S + 1e-8), row max ----------------
__global__ void k_norm() {
  int b = threadIdx.x;
  if (b >= 32 || blockIdx.x != 0) return;
  const float* P = g_pooled + b * 3136;
  float s = 0.f;
  for (int i = 0; i < 3136; ++i) s = s + P[i];
  float lm = -INFINITY;
  for (int i = 0; i < 3136; ++i) {
    float fl = P[i] / s;
    float lg = logf(fl + 1e-8f);
    g_logits[b * 3136 + i] = lg;
    lm = fmaxf(lm, lg);
  }
  g_lmax[b] = lm;
}

// ---------------- out = x ----------------
__global__ __launch_bounds__(256) void k_copy(const float4* __restrict__ x, float4* __restrict__ out) {
  int i = blockIdx.x * 256 + threadIdx.x;           // 1,605,632 float4 exactly
  out[i] = x[i];
}

// ---------------- JAX threefry2x32, key = (0, 42), partitionable 32-bit bits ----------------
__device__ __forceinline__ uint32_t rotl32(uint32_t x, int r) { return (x << r) | (x >> (32 - r)); }
__device__ __forceinline__ void threefry2x32(uint32_t x0, uint32_t x1, uint32_t& o0, uint32_t& o1) {
  const uint32_t ks0 = 0u, ks1 = 42u, ks2 = 0x1BD11BDAu ^ 0u ^ 42u;
  x0 += ks0; x1 += ks1;
#define TFR(r) { x0 += x1; x1 = rotl32(x1, (r)); x1 ^= x0; }
  TFR(13) TFR(15) TFR(26) TFR(6)  x0 += ks1; x1 += ks2 + 1u;
  TFR(17) TFR(29) TFR(16) TFR(24) x0 += ks2; x1 += ks0 + 2u;
  TFR(13) TFR(15) TFR(26) TFR(6)  x0 += ks0; x1 += ks1 + 3u;
  TFR(17) TFR(29) TFR(16) TFR(24) x0 += ks1; x1 += ks2 + 4u;
  TFR(13) TFR(15) TFR(26) TFR(6)  x0 += ks2; x1 += ks0 + 5u;
#undef TFR
  o0 = x0; o1 = x1;
}

__device__ __forceinline__ uint32_t random_bits_at(uint32_t idx) {
  uint32_t o0, o1; threefry2x32(0u, idx, o0, o1);   // counter = (hi,lo) of flat idx
  return o0 ^ o1;                                    // 32-bit partitionable combine
}

// Exact-value gumbel (OCML logf) -- the winner-deciding path, unchanged from R6.
__device__ __forceinline__ float gumbel_ocml(uint32_t mant) {
  float uni;
  if (mant == 0u) uni = 1.17549435e-38f;            // max(tiny, 0*(1-tiny)+tiny)
  else uni = __uint_as_float(0x3f800000u | mant) - 1.0f;  // exact
  float l1 = logf(uni);
  float n1 = -l1;
  float l2 = logf(n1);
  return -l2;
}

// Analytic sound screen threshold (replaces the 23-step double-log binary search):
// skip mant < mstar. g_true(u) <= T-1e-3  <=>  u <= exp(-exp(-(T-1e-3))).
// Error budget: logf impl |g-g_true| <= ~2e-6, T f32 rounding <= 1e-6 (inside the
// 1e-3 margin); expf-chain rel err <= 5e-7 -> <= 4.2 mant ulps (inside the -8 slack).
__device__ __forceinline__ uint32_t mstar_from(float M, float Lm) {
  float T = M - Lm - 1e-3f;
  if (!(T > -80.0f)) return 0u;                     // -inf / NaN safe
  float u_thr = expf(-expf(-T));
  int m = (int)(u_thr * 8388608.0f) - 8;
  return m > 0 ? (uint32_t)m : 0u;
}

// ---------------- categorical sampling: one task per (s,r,half) ----------------
__global__ __launch_bounds__(256) void k_samp() {
  int task = blockIdx.x * 256 + threadIdx.x;        // < NTASK2 (5008*256 exactly)
  int t = task >> 1;                // (s,r) id
  int h = task & 1;                 // half
  int r = t & 2047;
  int b = r >> 6;
  const float* L = g_logits + b * 3136;
  float Lm = g_lmax[b];
  uint32_t base = (uint32_t)t * 3136u;  // flat gumbel index base, < 2^31
  int j0 = h * 1568, j1 = j0 + 1568;
  float M = -INFINITY; int jstar = j0;
  uint32_t mstar = 0u;
  for (int j = j0; j < j1; ++j) {
    uint32_t bits = random_bits_at(base + (uint32_t)j);
    uint32_t mant = bits >> 9;
    if (mant < mstar) continue;     // sound skip: val certainly <= M
    float val = L[j] + gumbel_ocml(mant);
    if (val > M) { M = val; jstar = j; mstar = mstar_from(M, Lm); }
  }
  g_pM[task] = M;
  g_pJ[task] = jstar;
}

// ---------------- merge halves: strict > keeps first-occurrence argmax ----------------
__global__ __launch_bounds__(256) void k_merge(float* __restrict__ out) {
  int t = blockIdx.x * 256 + threadIdx.x;           // < NSAMP_T (2504*256 exactly)
  float M0 = g_pM[2 * t], M1 = g_pM[2 * t + 1];
  int j = (M1 > M0) ? g_pJ[2 * t + 1] : g_pJ[2 * t];
  int r = t & 2047;
  out[(size_t)r * 3136 + (size_t)j] = 0.0f;
}

// ---------------- launch ----------------
extern "C" void kernel_launch(void* const* d_in, const int* in_sizes, int n_in,
                              void* d_out, int out_size, void* d_ws, size_t ws_size,
                              hipStream_t stream) {
  (void)in_sizes; (void)n_in; (void)d_ws; (void)ws_size; (void)out_size;
  const float* x_old = (const float*)d_in[0];
  const float* x     = (const float*)d_in[1];
  float* out = (float*)d_out;

  k_rng  <<<1,     64, 0, stream>>>();
  k_dist <<<14112, 256, 0, stream>>>(x_old);
  k_mean1<<<NMEANB,256, 0, stream>>>();
  k_mean2<<<1,     64, 0, stream>>>();
  k_prob1<<<1568,  256, 0, stream>>>();
  k_pool <<<392,   256, 0, stream>>>();
  k_norm <<<1,     64, 0, stream>>>();
  k_copy <<<6272,  256, 0, stream>>>((const float4*)x, (float4*)out);
  k_samp <<<5008,  256, 0, stream>>>();
  k_merge<<<2504,  256, 0, stream>>>(out);
}